// Round 6
// baseline (523.746 us; speedup 1.0000x reference)
//
#include <hip/hip_runtime.h>

#define NEGV -10000.0f
#define BB 1024
#define TT 512
#define KK 64

typedef float vf2 __attribute__((ext_vector_type(2)));

__device__ __forceinline__ vf2 vmax2(vf2 a, vf2 b)
{
    return vf2{fmaxf(a.x, b.x), fmaxf(a.y, b.y)};
}
__device__ __forceinline__ int imin3(int a, int b, int c) { return min(min(a, b), c); }

// ---------------------------------------------------------------------------
// K0: trans = log_softmax(A + inv_mask*NEG, axis=-1). (unchanged)
// ---------------------------------------------------------------------------
__global__ __launch_bounds__(64)
void trans_kernel(const float* __restrict__ A, const int* __restrict__ inv,
                  float* __restrict__ trans)
{
    const int i = blockIdx.x, j = threadIdx.x;
    float x = A[i * KK + j] + (inv[i * KK + j] ? NEGV : 0.0f);
    float m = x;
    #pragma unroll
    for (int o = 32; o > 0; o >>= 1) m = fmaxf(m, __shfl_xor(m, o));
    float e = expf(x - m);
    float s = e;
    #pragma unroll
    for (int o = 32; o > 0; o >>= 1) s += __shfl_xor(s, o);
    trans[i * KK + j] = (x - m) - logf(s);
}

// ---------------------------------------------------------------------------
// K1: fused Viterbi — R14: SINGLE-WAVE blocks, zero s_barrier.
// R12/R13 calibration: 1327cy/step wall vs ~480cy issue -> ~850cy/step was
// s_barrier rendezvous across SIMDs + LDS RT. Fix: 64-thread block = 1 wave;
// lane j computes the FULL 64-way max/argmax for its own tag (64 adds, VALU
// was 65% idle). Alpha broadcast = intra-wave LDS RT: ds_write sA[j] ->
// lgkmcnt(0) (~40cy, own write only; same-wave DS ops process in order) ->
// 16x ds_read_b128 broadcast (same addr across lanes = conflict-free).
// Reads for step t+1 issue right after the write; the ~160-instr argmax
// encode of step t fills their latency. No cross-half merge needed at all.
// Occupancy: 1024 blocks / 256 CU = 4 blocks/CU = 1 wave/SIMD (LDS 33KB x4);
// __launch_bounds__(64,1) unlocks 256 VGPR (Tr 64 + av 64 + sv 64 + temps).
// ---------------------------------------------------------------------------

#define FILL4(BUF_, RB_)                                                       \
  { _Pragma("unroll")                                                          \
    for (int d_ = 0; d_ < 4; ++d_) {                                           \
        int r_ = (RB_) + d_; if (r_ > TT - 1) r_ = TT - 1;                     \
        BUF_[d_] = ur[r_ * KK + j];                                            \
    } }

#define STEP(T_, UV_)                                                          \
  {                                                                            \
    /* sv element i = alpha[i] + trans[i][j]; sv2[p] = elements {2p, 2p+1} */  \
    vf2 sv2[32];                                                               \
    _Pragma("unroll")                                                          \
    for (int q = 0; q < 16; ++q) {                                             \
        sv2[2 * q]     = vf2{av[q].x, av[q].y} + Tr2[2 * q];                   \
        sv2[2 * q + 1] = vf2{av[q].z, av[q].w} + Tr2[2 * q + 1];               \
    }                                                                          \
    /* 64-way max: packed pairwise tree (31 pk_max + 1 max) */                 \
    vf2 x16[16];                                                               \
    _Pragma("unroll")                                                          \
    for (int i = 0; i < 16; ++i) x16[i] = vmax2(sv2[i], sv2[i + 16]);          \
    vf2 x8[8];                                                                 \
    _Pragma("unroll")                                                          \
    for (int i = 0; i < 8; ++i) x8[i] = vmax2(x16[i], x16[i + 8]);             \
    vf2 x4[4];                                                                 \
    _Pragma("unroll")                                                          \
    for (int i = 0; i < 4; ++i) x4[i] = vmax2(x8[i], x8[i + 4]);               \
    vf2 x2a = vmax2(x4[0], x4[2]), x2b = vmax2(x4[1], x4[3]);                  \
    vf2 x1  = vmax2(x2a, x2b);                                                 \
    const float m = fmaxf(x1.x, x1.y);          /* max over all 64 i */        \
    float u_ = (UV_);                                                          \
    asm volatile("" : "+v"(u_));                                               \
    if ((T_) <= len) alpha = m + u_;     /* len uniform -> scalar branch */    \
    sA[j] = alpha;                                                             \
    /* drain own write (~40cy), then issue next-step broadcast reads; the */   \
    /* encode below fills their latency. Same-wave DS is in-order.        */   \
    asm volatile("s_waitcnt lgkmcnt(0)" ::: "memory");                         \
    {                                                                          \
        const float4* p = (const float4*)sA;                                   \
        _Pragma("unroll")                                                      \
        for (int q = 0; q < 16; ++q) av[q] = p[q];                             \
    }                                                                          \
    /* argmax encode vs m: sentinel 64, min3 tree = exact first index */       \
    {                                                                          \
        int c[64];                                                             \
        _Pragma("unroll")                                                      \
        for (int i = 0; i < 64; ++i)                                           \
            c[i] = (sv2[i >> 1][i & 1] == m) ? i : 64;                         \
        int m0[22];                                                            \
        _Pragma("unroll")                                                      \
        for (int i = 0; i < 21; ++i)                                           \
            m0[i] = imin3(c[3 * i], c[3 * i + 1], c[3 * i + 2]);               \
        m0[21] = c[63];                                                        \
        int m1[8];                                                             \
        _Pragma("unroll")                                                      \
        for (int i = 0; i < 7; ++i)                                            \
            m1[i] = imin3(m0[3 * i], m0[3 * i + 1], m0[3 * i + 2]);            \
        m1[7] = m0[21];                                                        \
        int bpi = imin3(imin3(m1[0], m1[1], m1[2]),                            \
                        imin3(m1[3], m1[4], m1[5]),                            \
                        min(m1[6], m1[7]));                                    \
        if ((T_) >= 2 && (T_) <= len)                                          \
            sbp[((T_) - 2) * KK + j] = (unsigned char)bpi;                     \
    }                                                                          \
  }

__global__ __launch_bounds__(64, 1)
void viterbi_kernel(const float* __restrict__ unary, const int* __restrict__ lengths,
                    const float* __restrict__ trans, int* __restrict__ out)
{
    const int j = threadIdx.x;                     // lane = output tag
    const int b = blockIdx.x;

    __shared__ unsigned char sbp[(TT - 1) * KK];   // bp rows t=2..512
    __shared__ __align__(16) float sA[KK];         // alpha broadcast (1 wave, in-order DS)

    // Tr2[p] = {trans[2p][j], trans[2p+1][j]} — all 64 incoming tags
    vf2 Tr2[32];
    #pragma unroll
    for (int p = 0; p < 32; ++p) {
        Tr2[p].x = trans[(2 * p)     * KK + j];
        Tr2[p].y = trans[(2 * p + 1) * KK + j];
    }

    const int len = lengths[b];                    // 1..512, uniform per block
    const float* ur = unary + (long)b * (TT * KK);
    int* orow = out + b * TT;

    // unary prefetch, 4-row double-buffered batches (global -> vmcnt, does not
    // interact with the lgkmcnt gate)
    float ub0[4], ub1[4];
    FILL4(ub0, 0) FILL4(ub1, 4)                    // rows 0..7 for t=1..8

    float alpha = (j == 1) ? 0.0f : NEGV;          // GO frame
    sA[j] = alpha;
    asm volatile("s_waitcnt lgkmcnt(0)" ::: "memory");

    float4 av[16];                                 // full alpha broadcast
    {
        const float4* p = (const float4*)sA;
        #pragma unroll
        for (int q = 0; q < 16; ++q) av[q] = p[q];
    }

    for (int tb = 1; tb <= len; tb += 8) {
        STEP(tb + 0, ub0[0]) STEP(tb + 1, ub0[1])
        STEP(tb + 2, ub0[2]) STEP(tb + 3, ub0[3])
        FILL4(ub0, tb + 7)                         // rows for t = tb+8..tb+11
        STEP(tb + 4, ub1[0]) STEP(tb + 5, ub1[1])
        STEP(tb + 6, ub1[2]) STEP(tb + 7, ub1[3])
        FILL4(ub1, tb + 11)                        // rows for t = tb+12..tb+15
    }

    // last = first-index argmax of final alpha (lane j holds alpha[j])
    float mm = alpha;
    #pragma unroll
    for (int o = 32; o > 0; o >>= 1) mm = fmaxf(mm, __shfl_xor(mm, o));
    unsigned long long msk = __ballot(alpha == mm);
    int last = __ffsll(msk) - 1;

    for (int jj = len - 1 + j; jj < TT; jj += 64) orow[jj] = last;

    asm volatile("s_waitcnt lgkmcnt(0)" ::: "memory");   // settle own DS queue

    // backward: pure LDS pointer chase (same wave wrote all sbp rows)
    int tag = last;
    for (int t = len; t >= 2; --t) {
        int prev = sbp[(t - 2) * KK + tag];        // same-address broadcast read
        if (j == 0) orow[t - 2] = prev;
        tag = prev;
    }
}

extern "C" void kernel_launch(void* const* d_in, const int* in_sizes, int n_in,
                              void* d_out, int out_size, void* d_ws, size_t ws_size,
                              hipStream_t stream)
{
    const float* unary   = (const float*)d_in[0];
    const int*   lengths = (const int*)d_in[1];
    const int*   inv     = (const int*)d_in[2];
    const float* A       = (const float*)d_in[3];
    int*         out     = (int*)d_out;

    float* trans = (float*)d_ws;                   // 4096 floats = 16 KB

    trans_kernel<<<KK, KK, 0, stream>>>(A, inv, trans);
    viterbi_kernel<<<BB, 64, 0, stream>>>(unary, lengths, trans, out);
}

// Round 7
// 513.582 us; speedup vs baseline: 1.0198x; 1.0198x over previous
//
#include <hip/hip_runtime.h>

#define NEGV -10000.0f
#define BB 1024
#define TT 512
#define KK 64

typedef float vf2 __attribute__((ext_vector_type(2)));

__device__ __forceinline__ vf2 vmax2(vf2 a, vf2 b)
{
    return vf2{fmaxf(a.x, b.x), fmaxf(a.y, b.y)};
}
__device__ __forceinline__ int imin3(int a, int b, int c) { return min(min(a, b), c); }

// ---------------------------------------------------------------------------
// K0: trans = log_softmax(A + inv_mask*NEG, axis=-1). (unchanged)
// ---------------------------------------------------------------------------
__global__ __launch_bounds__(64)
void trans_kernel(const float* __restrict__ A, const int* __restrict__ inv,
                  float* __restrict__ trans)
{
    const int i = blockIdx.x, j = threadIdx.x;
    float x = A[i * KK + j] + (inv[i * KK + j] ? NEGV : 0.0f);
    float m = x;
    #pragma unroll
    for (int o = 32; o > 0; o >>= 1) m = fmaxf(m, __shfl_xor(m, o));
    float e = expf(x - m);
    float s = e;
    #pragma unroll
    for (int o = 32; o > 0; o >>= 1) s += __shfl_xor(s, o);
    trans[i * KK + j] = (x - m) - logf(s);
}

// ---------------------------------------------------------------------------
// K1: fused Viterbi — R15: single-wave blocks (no s_barrier), schedule PINNED.
// R14 post-mortem: VGPR=132 revealed the compiler sank the 16 broadcast
// ds_reads AFTER the encode to save registers -> read latency (~280cy) landed
// naked on the serial chain (no 2nd wave to hide it at 1 wave/SIMD). Fixes:
// (a) drop the per-step lgkmcnt(0) drain — same-wave DS ops process in order,
//     the reads issued after the sA write see the new value; the compiler
//     still emits the consumer-side lgkm wait before the adds;
// (b) issue all 16 ds_read_b128 right after the write, then
//     sched_barrier(0) so the ~380cy encode MUST issue after them and cover
//     their latency. At 1 wave/SIMD the full 256-VGPR file is available;
//     trading regs (~230 live) for overlap is free.
// Expected ~570cy/step issue-bound vs R14's 1770.
// ---------------------------------------------------------------------------

#define FILL4(BUF_, RB_)                                                       \
  { _Pragma("unroll")                                                          \
    for (int d_ = 0; d_ < 4; ++d_) {                                           \
        int r_ = (RB_) + d_; if (r_ > TT - 1) r_ = TT - 1;                     \
        BUF_[d_] = ur[r_ * KK + j];                                            \
    } }

#define STEP(T_, UV_)                                                          \
  {                                                                            \
    /* sv element i = alpha[i] + trans[i][j]; sv2[p] = elements {2p, 2p+1} */  \
    vf2 sv2[32];                                                               \
    _Pragma("unroll")                                                          \
    for (int q = 0; q < 16; ++q) {                                             \
        sv2[2 * q]     = vf2{av[q].x, av[q].y} + Tr2[2 * q];                   \
        sv2[2 * q + 1] = vf2{av[q].z, av[q].w} + Tr2[2 * q + 1];               \
    }                                                                          \
    /* 64-way max: packed pairwise tree (31 pk_max + 1 max) */                 \
    vf2 x16[16];                                                               \
    _Pragma("unroll")                                                          \
    for (int i = 0; i < 16; ++i) x16[i] = vmax2(sv2[i], sv2[i + 16]);          \
    vf2 x8[8];                                                                 \
    _Pragma("unroll")                                                          \
    for (int i = 0; i < 8; ++i) x8[i] = vmax2(x16[i], x16[i + 8]);             \
    vf2 x4[4];                                                                 \
    _Pragma("unroll")                                                          \
    for (int i = 0; i < 4; ++i) x4[i] = vmax2(x8[i], x8[i + 4]);               \
    vf2 x2a = vmax2(x4[0], x4[2]), x2b = vmax2(x4[1], x4[3]);                  \
    vf2 x1  = vmax2(x2a, x2b);                                                 \
    const float m = fmaxf(x1.x, x1.y);          /* max over all 64 i */        \
    float u_ = (UV_);                                                          \
    asm volatile("" : "+v"(u_));                                               \
    if ((T_) <= len) alpha = m + u_;     /* len uniform -> scalar branch */    \
    sA[j] = alpha;                       /* ds_write; in-order DS queue */     \
    /* next-step broadcast reads issue NOW (see the write: same-wave order) */ \
    {                                                                          \
        const float4* p = (const float4*)sA;                                   \
        _Pragma("unroll")                                                      \
        for (int q = 0; q < 16; ++q) av[q] = p[q];                             \
    }                                                                          \
    /* pin: encode must not be hoisted above the reads, reads must not sink */ \
    __builtin_amdgcn_sched_barrier(0);                                         \
    /* argmax encode vs m: sentinel 64, min3 tree = exact first index.     */  \
    /* ~380cy of issue here covers the reads' ~280cy latency.              */  \
    {                                                                          \
        int c[64];                                                             \
        _Pragma("unroll")                                                      \
        for (int i = 0; i < 64; ++i)                                           \
            c[i] = (sv2[i >> 1][i & 1] == m) ? i : 64;                         \
        int m0[22];                                                            \
        _Pragma("unroll")                                                      \
        for (int i = 0; i < 21; ++i)                                           \
            m0[i] = imin3(c[3 * i], c[3 * i + 1], c[3 * i + 2]);               \
        m0[21] = c[63];                                                        \
        int m1[8];                                                             \
        _Pragma("unroll")                                                      \
        for (int i = 0; i < 7; ++i)                                            \
            m1[i] = imin3(m0[3 * i], m0[3 * i + 1], m0[3 * i + 2]);            \
        m1[7] = m0[21];                                                        \
        int bpi = imin3(imin3(m1[0], m1[1], m1[2]),                            \
                        imin3(m1[3], m1[4], m1[5]),                            \
                        min(m1[6], m1[7]));                                    \
        if ((T_) >= 2 && (T_) <= len)                                          \
            sbp[((T_) - 2) * KK + j] = (unsigned char)bpi;                     \
    }                                                                          \
  }

__global__ __launch_bounds__(64, 1)
void viterbi_kernel(const float* __restrict__ unary, const int* __restrict__ lengths,
                    const float* __restrict__ trans, int* __restrict__ out)
{
    const int j = threadIdx.x;                     // lane = output tag
    const int b = blockIdx.x;

    __shared__ unsigned char sbp[(TT - 1) * KK];   // bp rows t=2..512
    __shared__ __align__(16) float sA[KK];         // alpha broadcast (1 wave, in-order DS)

    // Tr2[p] = {trans[2p][j], trans[2p+1][j]} — all 64 incoming tags
    vf2 Tr2[32];
    #pragma unroll
    for (int p = 0; p < 32; ++p) {
        Tr2[p].x = trans[(2 * p)     * KK + j];
        Tr2[p].y = trans[(2 * p + 1) * KK + j];
    }

    const int len = lengths[b];                    // 1..512, uniform per block
    const float* ur = unary + (long)b * (TT * KK);
    int* orow = out + b * TT;

    // unary prefetch, 4-row double-buffered batches (global -> vmcnt, separate
    // counter from the DS traffic)
    float ub0[4], ub1[4];
    FILL4(ub0, 0) FILL4(ub1, 4)                    // rows 0..7 for t=1..8

    float alpha = (j == 1) ? 0.0f : NEGV;          // GO frame
    sA[j] = alpha;                                 // in-order: reads below see it

    float4 av[16];                                 // full alpha broadcast
    {
        const float4* p = (const float4*)sA;
        #pragma unroll
        for (int q = 0; q < 16; ++q) av[q] = p[q];
    }

    for (int tb = 1; tb <= len; tb += 8) {
        STEP(tb + 0, ub0[0]) STEP(tb + 1, ub0[1])
        STEP(tb + 2, ub0[2]) STEP(tb + 3, ub0[3])
        FILL4(ub0, tb + 7)                         // rows for t = tb+8..tb+11
        STEP(tb + 4, ub1[0]) STEP(tb + 5, ub1[1])
        STEP(tb + 6, ub1[2]) STEP(tb + 7, ub1[3])
        FILL4(ub1, tb + 11)                        // rows for t = tb+12..tb+15
    }

    // last = first-index argmax of final alpha (lane j holds alpha[j])
    float mm = alpha;
    #pragma unroll
    for (int o = 32; o > 0; o >>= 1) mm = fmaxf(mm, __shfl_xor(mm, o));
    unsigned long long msk = __ballot(alpha == mm);
    int last = __ffsll(msk) - 1;

    for (int jj = len - 1 + j; jj < TT; jj += 64) orow[jj] = last;

    asm volatile("s_waitcnt lgkmcnt(0)" ::: "memory");   // settle own DS queue

    // backward: pure LDS pointer chase (same wave wrote all sbp rows)
    int tag = last;
    for (int t = len; t >= 2; --t) {
        int prev = sbp[(t - 2) * KK + tag];        // same-address broadcast read
        if (j == 0) orow[t - 2] = prev;
        tag = prev;
    }
}

extern "C" void kernel_launch(void* const* d_in, const int* in_sizes, int n_in,
                              void* d_out, int out_size, void* d_ws, size_t ws_size,
                              hipStream_t stream)
{
    const float* unary   = (const float*)d_in[0];
    const int*   lengths = (const int*)d_in[1];
    const int*   inv     = (const int*)d_in[2];
    const float* A       = (const float*)d_in[3];
    int*         out     = (int*)d_out;

    float* trans = (float*)d_ws;                   // 4096 floats = 16 KB

    trans_kernel<<<KK, KK, 0, stream>>>(A, inv, trans);
    viterbi_kernel<<<BB, 64, 0, stream>>>(unary, lengths, trans, out);
}

// Round 8
// 513.103 us; speedup vs baseline: 1.0207x; 1.0009x over previous
//
#include <hip/hip_runtime.h>

#define NEGV -10000.0f
#define BB 1024
#define TT 512
#define KK 64

typedef float vf2 __attribute__((ext_vector_type(2)));

__device__ __forceinline__ vf2 vmax2(vf2 a, vf2 b)
{
    return vf2{fmaxf(a.x, b.x), fmaxf(a.y, b.y)};
}
__device__ __forceinline__ int imin3(int a, int b, int c) { return min(min(a, b), c); }

// ---------------------------------------------------------------------------
// K0: trans = log_softmax(A + inv_mask*NEG, axis=-1). (unchanged)
// ---------------------------------------------------------------------------
__global__ __launch_bounds__(64)
void trans_kernel(const float* __restrict__ A, const int* __restrict__ inv,
                  float* __restrict__ trans)
{
    const int i = blockIdx.x, j = threadIdx.x;
    float x = A[i * KK + j] + (inv[i * KK + j] ? NEGV : 0.0f);
    float m = x;
    #pragma unroll
    for (int o = 32; o > 0; o >>= 1) m = fmaxf(m, __shfl_xor(m, o));
    float e = expf(x - m);
    float s = e;
    #pragma unroll
    for (int o = 32; o > 0; o >>= 1) s += __shfl_xor(s, o);
    trans[i * KK + j] = (x - m) - logf(s);
}

// ---------------------------------------------------------------------------
// K1: fused Viterbi — R16: single-wave blocks; alpha-broadcast DS ops in
// INLINE ASM so the compiler cannot sink them (R15 post-mortem: VGPR stayed
// 132 -> IR sank the C-level reads past sched_barrier; MIR pin too late).
// Schedule per step (rule-#18 pattern, m214-verified):
//   s_waitcnt lgkmcnt(0); sched_barrier(0)   <- wait placed AFTER prior
//   adds(32 pk) -> max tree(32) -> alpha        step's encode covered latency
//   asm ds_write_b32 sA[j]; asm 16x ds_read_b128 (in-order same-wave DS)
//   sched_barrier(0); encode(~170) + sbp byte write
// LDS addrs as raw 32-bit offsets (low 32 bits of generic pointer — CK/HK
// idiom). av/sv2/Tr2 co-live -> VGPR ~210 (fine: 1 wave/SIMD has 256).
// ---------------------------------------------------------------------------

#define FILL4(BUF_, RB_)                                                       \
  { _Pragma("unroll")                                                          \
    for (int d_ = 0; d_ < 4; ++d_) {                                           \
        int r_ = (RB_) + d_; if (r_ > TT - 1) r_ = TT - 1;                     \
        BUF_[d_] = ur[r_ * KK + j];                                            \
    } }

#define DSR(IDX_, OFF_)                                                        \
    asm volatile("ds_read_b128 %0, %1 offset:" OFF_                            \
                 : "=v"(av[IDX_]) : "v"(ard))

#define STEP(T_, UV_)                                                          \
  {                                                                            \
    /* wait for the 16 reads issued LAST step (latency already covered by */   \
    /* last step's encode); fence so the adds can't hoist above the wait. */   \
    asm volatile("s_waitcnt lgkmcnt(0)" ::: "memory");                         \
    __builtin_amdgcn_sched_barrier(0);                                         \
    /* sv element i = alpha[i] + trans[i][j]; sv2[p] = elements {2p,2p+1} */   \
    vf2 sv2[32];                                                               \
    _Pragma("unroll")                                                          \
    for (int q = 0; q < 16; ++q) {                                             \
        sv2[2 * q]     = vf2{av[q].x, av[q].y} + Tr2[2 * q];                   \
        sv2[2 * q + 1] = vf2{av[q].z, av[q].w} + Tr2[2 * q + 1];               \
    }                                                                          \
    /* 64-way max: packed pairwise tree (31 pk_max + 1 max) */                 \
    vf2 x16[16];                                                               \
    _Pragma("unroll")                                                          \
    for (int i = 0; i < 16; ++i) x16[i] = vmax2(sv2[i], sv2[i + 16]);          \
    vf2 x8[8];                                                                 \
    _Pragma("unroll")                                                          \
    for (int i = 0; i < 8; ++i) x8[i] = vmax2(x16[i], x16[i + 8]);             \
    vf2 x4[4];                                                                 \
    _Pragma("unroll")                                                          \
    for (int i = 0; i < 4; ++i) x4[i] = vmax2(x8[i], x8[i + 4]);               \
    vf2 x2a = vmax2(x4[0], x4[2]), x2b = vmax2(x4[1], x4[3]);                  \
    vf2 x1  = vmax2(x2a, x2b);                                                 \
    const float m = fmaxf(x1.x, x1.y);          /* max over all 64 i */        \
    float u_ = (UV_);                                                          \
    asm volatile("" : "+v"(u_));                                               \
    if ((T_) <= len) alpha = m + u_;     /* len uniform -> scalar branch */    \
    /* DS round-trip, invisible to the compiler: write then 16 broadcast   */ \
    /* reads (same-wave DS executes in order -> reads see the write).      */ \
    asm volatile("ds_write_b32 %0, %1" :: "v"(awr), "v"(alpha));               \
    DSR(0,  "0");   DSR(1,  "16");  DSR(2,  "32");  DSR(3,  "48");             \
    DSR(4,  "64");  DSR(5,  "80");  DSR(6,  "96");  DSR(7,  "112");            \
    DSR(8,  "128"); DSR(9,  "144"); DSR(10, "160"); DSR(11, "176");            \
    DSR(12, "192"); DSR(13, "208"); DSR(14, "224"); DSR(15, "240");            \
    /* encode must issue after the reads (covers their latency) */             \
    __builtin_amdgcn_sched_barrier(0);                                         \
    /* argmax encode vs m: sentinel 64, min3 tree = exact first index */       \
    {                                                                          \
        int c[64];                                                             \
        _Pragma("unroll")                                                      \
        for (int i = 0; i < 64; ++i)                                           \
            c[i] = (sv2[i >> 1][i & 1] == m) ? i : 64;                         \
        int m0[22];                                                            \
        _Pragma("unroll")                                                      \
        for (int i = 0; i < 21; ++i)                                           \
            m0[i] = imin3(c[3 * i], c[3 * i + 1], c[3 * i + 2]);               \
        m0[21] = c[63];                                                        \
        int m1[8];                                                             \
        _Pragma("unroll")                                                      \
        for (int i = 0; i < 7; ++i)                                            \
            m1[i] = imin3(m0[3 * i], m0[3 * i + 1], m0[3 * i + 2]);            \
        m1[7] = m0[21];                                                        \
        int bpi = imin3(imin3(m1[0], m1[1], m1[2]),                            \
                        imin3(m1[3], m1[4], m1[5]),                            \
                        min(m1[6], m1[7]));                                    \
        if ((T_) >= 2 && (T_) <= len)                                          \
            sbp[((T_) - 2) * KK + j] = (unsigned char)bpi;                     \
    }                                                                          \
  }

__global__ __launch_bounds__(64, 1)
void viterbi_kernel(const float* __restrict__ unary, const int* __restrict__ lengths,
                    const float* __restrict__ trans, int* __restrict__ out)
{
    const int j = threadIdx.x;                     // lane = output tag
    const int b = blockIdx.x;

    __shared__ unsigned char sbp[(TT - 1) * KK];   // bp rows t=2..512
    __shared__ __align__(16) float sA[KK];         // alpha broadcast (1 wave)

    // raw LDS byte offsets for inline asm (low 32 bits of generic pointer)
    const unsigned ard = (unsigned)(unsigned long long)(const void*)sA;
    const unsigned awr = ard + 4u * (unsigned)j;

    // Tr2[p] = {trans[2p][j], trans[2p+1][j]} — all 64 incoming tags
    vf2 Tr2[32];
    #pragma unroll
    for (int p = 0; p < 32; ++p) {
        Tr2[p].x = trans[(2 * p)     * KK + j];
        Tr2[p].y = trans[(2 * p + 1) * KK + j];
    }

    const int len = lengths[b];                    // 1..512, uniform per block
    const float* ur = unary + (long)b * (TT * KK);
    int* orow = out + b * TT;

    // unary prefetch, 4-row double-buffered batches (global -> vmcnt, separate
    // counter from DS)
    float ub0[4], ub1[4];
    FILL4(ub0, 0) FILL4(ub1, 4)                    // rows 0..7 for t=1..8

    float alpha = (j == 1) ? 0.0f : NEGV;          // GO frame
    float4 av[16];                                 // full alpha broadcast

    // prologue: same asm pattern as the loop (write, 16 reads; STEP's top
    // wait covers them)
    asm volatile("ds_write_b32 %0, %1" :: "v"(awr), "v"(alpha));
    DSR(0,  "0");   DSR(1,  "16");  DSR(2,  "32");  DSR(3,  "48");
    DSR(4,  "64");  DSR(5,  "80");  DSR(6,  "96");  DSR(7,  "112");
    DSR(8,  "128"); DSR(9,  "144"); DSR(10, "160"); DSR(11, "176");
    DSR(12, "192"); DSR(13, "208"); DSR(14, "224"); DSR(15, "240");

    for (int tb = 1; tb <= len; tb += 8) {
        STEP(tb + 0, ub0[0]) STEP(tb + 1, ub0[1])
        STEP(tb + 2, ub0[2]) STEP(tb + 3, ub0[3])
        FILL4(ub0, tb + 7)                         // rows for t = tb+8..tb+11
        STEP(tb + 4, ub1[0]) STEP(tb + 5, ub1[1])
        STEP(tb + 6, ub1[2]) STEP(tb + 7, ub1[3])
        FILL4(ub1, tb + 11)                        // rows for t = tb+12..tb+15
    }

    // last = first-index argmax of final alpha (lane j holds alpha[j])
    float mm = alpha;
    #pragma unroll
    for (int o = 32; o > 0; o >>= 1) mm = fmaxf(mm, __shfl_xor(mm, o));
    unsigned long long msk = __ballot(alpha == mm);
    int last = __ffsll(msk) - 1;

    for (int jj = len - 1 + j; jj < TT; jj += 64) orow[jj] = last;

    asm volatile("s_waitcnt lgkmcnt(0)" ::: "memory");   // settle DS queue
    __builtin_amdgcn_sched_barrier(0);

    // backward: pure LDS pointer chase (same wave wrote all sbp rows)
    int tag = last;
    for (int t = len; t >= 2; --t) {
        int prev = sbp[(t - 2) * KK + tag];        // same-address broadcast read
        if (j == 0) orow[t - 2] = prev;
        tag = prev;
    }
}

extern "C" void kernel_launch(void* const* d_in, const int* in_sizes, int n_in,
                              void* d_out, int out_size, void* d_ws, size_t ws_size,
                              hipStream_t stream)
{
    const float* unary   = (const float*)d_in[0];
    const int*   lengths = (const int*)d_in[1];
    const int*   inv     = (const int*)d_in[2];
    const float* A       = (const float*)d_in[3];
    int*         out     = (int*)d_out;

    float* trans = (float*)d_ws;                   // 4096 floats = 16 KB

    trans_kernel<<<KK, KK, 0, stream>>>(A, inv, trans);
    viterbi_kernel<<<BB, 64, 0, stream>>>(unary, lengths, trans, out);
}

// Round 11
// 441.903 us; speedup vs baseline: 1.1852x; 1.1611x over previous
//
#include <hip/hip_runtime.h>

#define NEGV -10000.0f
#define BB 1024
#define TT 512
#define KK 64
#define BPROWS 512                                 // bp rows allocated per block

typedef float vf2 __attribute__((ext_vector_type(2)));
typedef int   vi2 __attribute__((ext_vector_type(2)));

// Raw barrier: own-wave LDS drain + s_barrier.
#define BAR() asm volatile("s_waitcnt lgkmcnt(0)\n\ts_barrier" ::: "memory")

// Cross-half pair merges via __builtin_amdgcn_permlane32_swap (R12-verified).
__device__ __forceinline__ float merge_max64(float v)
{
    vi2 r = __builtin_amdgcn_permlane32_swap(__float_as_int(v), __float_as_int(v),
                                             false, false);
    return fmaxf(__int_as_float(r[0]), __int_as_float(r[1]));
}
__device__ __forceinline__ int merge_min64(int v)
{
    vi2 r = __builtin_amdgcn_permlane32_swap(v, v, false, false);
    return min(r[0], r[1]);
}

// ---------------------------------------------------------------------------
// K0: trans = log_softmax(A + inv_mask*NEG, axis=-1). (unchanged)
// ---------------------------------------------------------------------------
__global__ __launch_bounds__(64)
void trans_kernel(const float* __restrict__ A, const int* __restrict__ inv,
                  float* __restrict__ trans)
{
    const int i = blockIdx.x, j = threadIdx.x;
    float x = A[i * KK + j] + (inv[i * KK + j] ? NEGV : 0.0f);
    float m = x;
    #pragma unroll
    for (int o = 32; o > 0; o >>= 1) m = fmaxf(m, __shfl_xor(m, o));
    float e = expf(x - m);
    float s = e;
    #pragma unroll
    for (int o = 32; o > 0; o >>= 1) s += __shfl_xor(s, o);
    trans[i * KK + j] = (x - m) - logf(s);
}

// ---------------------------------------------------------------------------
// K1: fused Viterbi. R18/R19: R13's proven two-wave structure, backpointers in
// GLOBAL ws. Occupancy forensics (R13-R16): 33.3KB sbp capped residency at
// ~2 blocks/CU (Occupancy 11%/6% = half the 4-block value) -> grid ran in ~2
// sequential rounds. LDS now ~8.7KB -> 4 blocks/CU, one round. Backward chase
// re-stages bp from global in 128-row (8KB) LDS chunks. R19 fixes R18's macro
// bug: bp-store passed as a function-like macro NAME (BP_G/BP_L), invoked as
// BPM_(T_) inside STEP so the step literal substitutes correctly.
// ---------------------------------------------------------------------------

__device__ __forceinline__ int imin3(int a, int b, int c) { return min(min(a, b), c); }

#define FILL4(BUF_, RB_)                                                       \
  { _Pragma("unroll")                                                          \
    for (int d_ = 0; d_ < 4; ++d_) {                                           \
        int r_ = (RB_) + d_; if (r_ > TT - 1) r_ = TT - 1;                     \
        BUF_[d_] = ur[r_ * KK + j];                                            \
    } }

// bp-store macros (invoked inside STEP via the BPM_ parameter)
#define BP_G(t) bpb[((t) - 2) * KK + j] = (unsigned char)bpi
#define BP_L(t) sbp[((t) - 2) * KK + j] = (unsigned char)bpi

// P_ = (T_)&1 parity for the sA double buffer; BPM_ = bp-store macro name.
#define STEP(T_, UV_, P_, BPM_)                                                \
  {                                                                            \
    /* ---- Phase A (pre-barrier critical path) ---- */                        \
    float sv[32];                                                              \
    _Pragma("unroll")                                                          \
    for (int q = 0; q < 8; ++q) {                                              \
        vf2 t01 = vf2{a4[q].x, a4[q].y} + Tr2[2 * q];                          \
        vf2 t23 = vf2{a4[q].z, a4[q].w} + Tr2[2 * q + 1];                      \
        sv[4 * q + 0] = t01.x; sv[4 * q + 1] = t01.y;                          \
        sv[4 * q + 2] = t23.x; sv[4 * q + 3] = t23.y;                          \
    }                                                                          \
    float l0[11];                                                              \
    _Pragma("unroll")                                                          \
    for (int i = 0; i < 10; ++i)                                               \
        l0[i] = fmaxf(fmaxf(sv[3 * i], sv[3 * i + 1]), sv[3 * i + 2]);         \
    l0[10] = fmaxf(sv[30], sv[31]);                                            \
    float l1a = fmaxf(fmaxf(l0[0], l0[1]), l0[2]);                             \
    float l1b = fmaxf(fmaxf(l0[3], l0[4]), l0[5]);                             \
    float l1c = fmaxf(fmaxf(l0[6], l0[7]), l0[8]);                             \
    float l1d = fmaxf(l0[9], l0[10]);                                          \
    float mw  = fmaxf(fmaxf(fmaxf(l1a, l1b), l1c), l1d);                       \
    const float m = merge_max64(mw);            /* merged max over all 64 i */ \
    float u_ = (UV_);                                                          \
    asm volatile("" : "+v"(u_));                                               \
    if ((T_) <= len) alpha = m + u_;     /* len uniform -> scalar branch */    \
    if (!ishi) sA[P_][j] = alpha;        /* lo lanes: alpha broadcast  */      \
    BAR(); /* both waves' sA[P_] halves visible */                             \
    /* ---- Phase B (post-barrier shadow) ---- */                              \
    {                                                                          \
        const float4* p = (const float4*)sA[P_] + (ibase >> 2);                \
        _Pragma("unroll")                                                      \
        for (int q = 0; q < 8; ++q) a4[q] = p[q];                              \
    }                                                                          \
    {                                                                          \
        int c[32];                                                             \
        _Pragma("unroll")                                                      \
        for (int i = 0; i < 32; ++i) c[i] = (sv[i] == m) ? i : 64;             \
        int n0[11];                                                            \
        _Pragma("unroll")                                                      \
        for (int i = 0; i < 10; ++i)                                           \
            n0[i] = imin3(c[3 * i], c[3 * i + 1], c[3 * i + 2]);               \
        n0[10] = min(c[30], c[31]);                                            \
        int n1a = imin3(n0[0], n0[1], n0[2]);                                  \
        int n1b = imin3(n0[3], n0[4], n0[5]);                                  \
        int n1c = imin3(n0[6], n0[7], n0[8]);                                  \
        int n1d = min(n0[9], n0[10]);                                          \
        int cmin = min(min(min(n1a, n1b), n1c), n1d) + ibase;                  \
        int bpi = merge_min64(cmin);            /* global first argmax */      \
        if (ishi && (T_) >= 2 && (T_) <= len) { BPM_(T_); }                    \
    }                                                                          \
  }

// common body prologue for both kernels
#define VIT_PROLOGUE()                                                         \
    const int tid   = threadIdx.x;                                             \
    const int wv    = tid >> 6;                                                \
    const int lane  = tid & 63;                                                \
    const int sub   = lane & 31;                                               \
    const int ibase = (lane >> 5) << 5;                                        \
    const bool ishi = (lane >= 32);                                            \
    const int j     = wv * 32 + sub;                                           \
    const int b     = blockIdx.x;                                              \
    vf2 Tr2[16];                                                               \
    _Pragma("unroll")                                                          \
    for (int q = 0; q < 16; ++q) {                                             \
        Tr2[q].x = trans[(ibase + 2 * q)     * KK + j];                        \
        Tr2[q].y = trans[(ibase + 2 * q + 1) * KK + j];                        \
    }                                                                          \
    const int len = lengths[b];                                                \
    const float* ur = unary + (long)b * (TT * KK);                             \
    int* orow = out + b * TT;                                                  \
    float ub0[4], ub1[4];                                                      \
    FILL4(ub0, 0) FILL4(ub1, 4)                                                \
    float alpha = (j == 1) ? 0.0f : NEGV;                                      \
    if (!ishi) sA[0][j] = alpha;                                               \
    BAR();                                                                     \
    float4 a4[8];                                                              \
    {                                                                          \
        const float4* p = (const float4*)sA[0] + (ibase >> 2);                 \
        _Pragma("unroll")                                                      \
        for (int q = 0; q < 8; ++q) a4[q] = p[q];                              \
    }

#define VIT_LOOP(BPM_)                                                         \
    for (int tb = 1; tb <= len; tb += 8) {                                     \
        STEP(tb + 0, ub0[0], 1, BPM_) STEP(tb + 1, ub0[1], 0, BPM_)            \
        STEP(tb + 2, ub0[2], 1, BPM_) STEP(tb + 3, ub0[3], 0, BPM_)            \
        FILL4(ub0, tb + 7)                                                     \
        STEP(tb + 4, ub1[0], 1, BPM_) STEP(tb + 5, ub1[1], 0, BPM_)            \
        STEP(tb + 6, ub1[2], 1, BPM_) STEP(tb + 7, ub1[3], 0, BPM_)            \
        FILL4(ub1, tb + 11)                                                    \
    }

#define VIT_LAST()                                                             \
    float av_ = sA[0][lane];                                                   \
    float mm = av_;                                                            \
    _Pragma("unroll")                                                          \
    for (int o = 32; o > 0; o >>= 1) mm = fmaxf(mm, __shfl_xor(mm, o));        \
    unsigned long long msk = __ballot(av_ == mm);                              \
    int last = __ffsll(msk) - 1;                                               \
    for (int jj = len - 1 + lane; jj < TT; jj += 64) orow[jj] = last;

// ---------------- primary kernel: bp in GLOBAL workspace ----------------
__global__ __launch_bounds__(128, 2)
void viterbi_kernel(const float* __restrict__ unary, const int* __restrict__ lengths,
                    const float* __restrict__ trans, unsigned char* __restrict__ bpg,
                    int* __restrict__ out)
{
    __shared__ __align__(16) float sA[2][KK];           // alpha dbuf (parity)
    __shared__ __align__(16) unsigned char chunk[8192]; // backward staging (128 rows)

    VIT_PROLOGUE()

    unsigned char* __restrict__ bpb = bpg + (long)b * (BPROWS * KK);

    VIT_LOOP(BP_G)

    // join: drain global bp stores (vmcnt) + LDS (lgkm), then barrier
    asm volatile("s_waitcnt vmcnt(0) lgkmcnt(0)\n\ts_barrier" ::: "memory");
    if (wv == 1) return;

    VIT_LAST()

    // backward: chunked global->LDS staging + LDS chase (wave0, 64 lanes)
    int tag = last;
    int t2 = len - 2;                              // bp row index for step t = t2+2
    while (t2 >= 0) {
        int base = t2 & ~127;                      // 128-row chunk
        {
            const int4* src = (const int4*)(bpb + base * KK);
            int4* dst = (int4*)chunk;
            #pragma unroll
            for (int k = 0; k < 8; ++k) dst[lane + 64 * k] = src[lane + 64 * k];
        }
        asm volatile("s_waitcnt vmcnt(0) lgkmcnt(0)" ::: "memory");
        for (; t2 >= base; --t2) {
            int prev = chunk[(t2 - base) * KK + tag];  // broadcast read
            if (lane == 0) orow[t2] = prev;
            tag = prev;
        }
    }
}

// ---------------- fallback kernel: bp in LDS (exact R13, 283us proven) ------
__global__ __launch_bounds__(128, 2)
void viterbi_kernel_lds(const float* __restrict__ unary, const int* __restrict__ lengths,
                        const float* __restrict__ trans, int* __restrict__ out)
{
    __shared__ unsigned char sbp[(TT - 1) * KK];
    __shared__ __align__(16) float sA[2][KK];

    VIT_PROLOGUE()

    VIT_LOOP(BP_L)

    BAR();                                         // publish final sbp rows
    if (wv == 1) return;

    VIT_LAST()

    asm volatile("s_waitcnt lgkmcnt(0)" ::: "memory");
    int tag = last;
    for (int t = len; t >= 2; --t) {
        int prev = sbp[(t - 2) * KK + tag];
        if (lane == 0) orow[t - 2] = prev;
        tag = prev;
    }
}

extern "C" void kernel_launch(void* const* d_in, const int* in_sizes, int n_in,
                              void* d_out, int out_size, void* d_ws, size_t ws_size,
                              hipStream_t stream)
{
    const float* unary   = (const float*)d_in[0];
    const int*   lengths = (const int*)d_in[1];
    const int*   inv     = (const int*)d_in[2];
    const float* A       = (const float*)d_in[3];
    int*         out     = (int*)d_out;

    float* trans = (float*)d_ws;                   // 4096 floats = 16 KB
    unsigned char* bpg = (unsigned char*)d_ws + 16 * 1024;

    trans_kernel<<<KK, KK, 0, stream>>>(A, inv, trans);

    const size_t need = 16 * 1024 + (size_t)BB * (BPROWS * KK);  // ~33.6 MB
    if (ws_size >= need) {
        viterbi_kernel<<<BB, 128, 0, stream>>>(unary, lengths, trans, bpg, out);
    } else {
        viterbi_kernel_lds<<<BB, 128, 0, stream>>>(unary, lengths, trans, out);
    }
}